// Round 3
// baseline (26424.985 us; speedup 1.0000x reference)
//
#include <hip/hip_runtime.h>
#include <hip/hip_bf16.h>
#include <cstdint>
#include <cstddef>
#include <cstring>

using u32 = unsigned int;
using u64 = unsigned long long;
typedef _Float16 h2 __attribute__((ext_vector_type(2)));
typedef _Float16 h4 __attribute__((ext_vector_type(4)));

constexpr int B_=64, T_=600, U_=50, V_=77, H_=400, OUT_=121;
constexpr int G1=50, GPA=16, G2=50, G3=50, GOUT=8;
constexpr int NBLK = G1+GPA+G2+G3+GOUT; // 174
// counter targets per stage
constexpr u32 CNT0=50, CNT1=16, CNT2=50, CNT3=50;

// ---- ws byte offsets ----
constexpr size_t FLAGS_B = 0;                        // [stage4][t600] 64B counter slots
constexpr size_t FLAGS_SZ = 4ull*600*64;             // 153,600
constexpr size_t W1F_B  = FLAGS_SZ;                  // interleaved f16 [kk][cu8][g4][h4]
constexpr size_t W1WG   = 120ull*128;
constexpr size_t W2F_B  = W1F_B + 50ull*W1WG*2;
constexpr size_t W2WG   = 220ull*128;
constexpr size_t W3F_B  = W2F_B + 50ull*W2WG*2;
constexpr size_t WOF_B  = W3F_B + 50ull*W2WG*2;      // 8 * [kk300][cg32][c4][h4]
constexpr size_t WOWG   = 300ull*32*16;
constexpr size_t GMIX_B = WOF_B + 8ull*WOWG*2;       // f32 [600][64][32]  mix pre-activation
constexpr size_t GMIX_SZ= 600ull*64*32*4;            // 4,915,200
// write-once, t-indexed inter-stage buffers (consumers: plain CACHED loads)
constexpr size_t FWV_B  = GMIX_B + GMIX_SZ;          // u32 [600][64][40]  (wv+x, PA)
constexpr size_t FH1_B  = FWV_B + 600ull*64*40*4;    // u32 [600][64][200] (h1, L1)
constexpr size_t FH2_B  = FH1_B + 600ull*64*200*4;   // (h2, L2)
constexpr size_t FH3_B  = FH2_B + 600ull*64*200*4;   // (h3, L3)
// total ~113 MB

// LDS strides (f16 units)
constexpr int SW1 = 180;   // L1 panels (160 dims)
constexpr int SW2 = 228;   // L2/L3 panels (220 dims)
constexpr int SWO = 244;   // OUT (240 dims)
constexpr int SMEM_BYTES = 58368;
// L1 LDS layout (bytes):
//   panA u32[64][90]   @ 0      (23040)
//   panB u32[64][90]   @ 23040  (23040)
//   kapS f32[64][10]   @ 46080  (2560)   persistent kappa state
//   hsl  f32[64][8]    @ 48640  (2048)   h1 slice for mix partials
//   wwinL f32[30][8]   @ 50688  (960)    w_win slice
//   overlays (dead-panel reuse during window phase):
//   mixT f32[64][30]   @ 0      (in panA)
//   wvs  f32[64][77]   @ 23040  (in panB)

struct P {
  const float *x, *tmask, *h0, *c0, *pwv, *pkap;
  const int *text;
  const float *wih1,*whh1,*bih1,*bhh1;
  const float *wih2,*whh2,*bih2,*bhh2;
  const float *wih3,*whh3,*bih3,*bhh3;
  const float *wwin,*bwin,*wout,*bout;
  float *out_y,*out_wv,*out_kap;
  _Float16 *w1f,*w2f,*w3f,*wof;
  float *gmix;
  u32 *fwv,*fh1,*fh2,*fh3;
  u32 *flags;
};

__device__ __forceinline__ u32 ldc_u(const u32* p) {
  return __hip_atomic_load((u32*)p, __ATOMIC_RELAXED, __HIP_MEMORY_SCOPE_AGENT);
}
__device__ __forceinline__ void stc_u(u32* p, u32 v) {
  __hip_atomic_store(p, v, __ATOMIC_RELAXED, __HIP_MEMORY_SCOPE_AGENT);
}
__device__ __forceinline__ void gaddf(float* p, float v) {
#if __has_builtin(__builtin_amdgcn_global_atomic_fadd_f32)
  __builtin_amdgcn_global_atomic_fadd_f32(p, v);
#else
  unsafeAtomicAdd(p, v);
#endif
}
__device__ __forceinline__ float sigm(float x) { return 1.f/(1.f+__expf(-x)); }
__device__ __forceinline__ h2 pk16(float a, float b) {
  auto t = __builtin_amdgcn_cvt_pkrtz(a, b);
  h2 r; memcpy(&r, &t, 4); return r;
}
__device__ __forceinline__ u32 h2u(h2 v) { u32 r; memcpy(&r, &v, 4); return r; }
__device__ __forceinline__ h2 u2h(u32 v) { h2 r; memcpy(&r, &v, 4); return r; }
__device__ __forceinline__ u32 pkf(float a, float b) { return h2u(pk16(a, b)); }
__device__ __forceinline__ float dot2(h2 a, h2 b, float c) { return __builtin_amdgcn_fdot2(a, b, c, false); }
__device__ __forceinline__ h2 lo4(h4 v) { return __builtin_shufflevector(v, v, 0, 1); }
__device__ __forceinline__ h2 hi4(h4 v) { return __builtin_shufflevector(v, v, 2, 3); }

// ---- single-counter barriers ----
__device__ __forceinline__ void wait_cnt(u32* cnt, int stage, int t, u32 target) {
  if (threadIdx.x == 0) {
    const u32* s = cnt + ((size_t)stage*600 + t)*16;
    while (ldc_u(s) < target) {}
  }
  __syncthreads();
}
// combined: stageA(t) and (t>0) stageB(t-1)
__device__ __forceinline__ void wait_cnt2(u32* cnt, int stageA, int t, u32 tgtA,
                                          int stageB, u32 tgtB) {
  if (threadIdx.x == 0) {
    const u32* sA = cnt + ((size_t)stageA*600 + t)*16;
    while (ldc_u(sA) < tgtA) {}
    if (t > 0) {
      const u32* sB = cnt + ((size_t)stageB*600 + (t-1))*16;
      while (ldc_u(sB) < tgtB) {}
    }
  }
  __syncthreads();
}
__device__ __forceinline__ void add_cnt(u32* cnt, int stage, int t) {
  if (threadIdx.x == 0)
    (void)__hip_atomic_fetch_add(cnt + ((size_t)stage*600 + t)*16, 1u,
                                 __ATOMIC_RELAXED, __HIP_MEMORY_SCOPE_AGENT);
}

template<int PH>
__device__ __forceinline__ void gemm_phase(const _Float16* pan, int SWf, const _Float16* wgW,
                                           int cu, int kbase, int b0, float acc[2][4]) {
  const _Float16* a0 = pan + b0*SWf;
  const _Float16* a1 = a0 + SWf;
  const _Float16* wp = wgW + ((size_t)(kbase >> 2) * 8 + cu) * 16;
#pragma unroll 4
  for (int k = 0; k < PH; k += 4) {
    h4 x0 = *(const h4*)(a0+k), x1 = *(const h4*)(a1+k);
    h4 wa = *(const h4*)(wp);
    h4 wb = *(const h4*)(wp+4);
    h4 wc = *(const h4*)(wp+8);
    h4 wd = *(const h4*)(wp+12);
    wp += 128;
    h2 x0l=lo4(x0), x0h=hi4(x0), x1l=lo4(x1), x1h=hi4(x1);
    acc[0][0]=dot2(x0l,lo4(wa),acc[0][0]); acc[0][0]=dot2(x0h,hi4(wa),acc[0][0]);
    acc[0][1]=dot2(x0l,lo4(wb),acc[0][1]); acc[0][1]=dot2(x0h,hi4(wb),acc[0][1]);
    acc[0][2]=dot2(x0l,lo4(wc),acc[0][2]); acc[0][2]=dot2(x0h,hi4(wc),acc[0][2]);
    acc[0][3]=dot2(x0l,lo4(wd),acc[0][3]); acc[0][3]=dot2(x0h,hi4(wd),acc[0][3]);
    acc[1][0]=dot2(x1l,lo4(wa),acc[1][0]); acc[1][0]=dot2(x1h,hi4(wa),acc[1][0]);
    acc[1][1]=dot2(x1l,lo4(wb),acc[1][1]); acc[1][1]=dot2(x1h,hi4(wb),acc[1][1]);
    acc[1][2]=dot2(x1l,lo4(wc),acc[1][2]); acc[1][2]=dot2(x1h,hi4(wc),acc[1][2]);
    acc[1][3]=dot2(x1l,lo4(wd),acc[1][3]); acc[1][3]=dot2(x1h,hi4(wd),acc[1][3]);
  }
}

// ================= L1 (self-sufficient: computes wv in-block from gmix) =================
__device__ void lstm1_role(const P& p, int wg, char* smem) {
  const int tid = threadIdx.x, cg = tid & 7, tb = tid >> 3;
  const int u = wg*8 + cg, b0 = tb*2;
  _Float16* panA = (_Float16*)smem;
  _Float16* panB = panA + 64*SW1;
  float* kapS  = (float*)(smem + 46080);
  float* hsl   = (float*)(smem + 48640);
  float* wwinL = (float*)(smem + 50688);
  float* mixT  = (float*)smem;             // overlay panA
  float* wvs   = (float*)(smem + 23040);   // overlay panB
  _Float16* wgW = p.w1f + (size_t)wg * W1WG;
  // K-order dims: [h1rec 0..399 | wv 400..476 | x 477..479]
  for (int e = tid; e < 32*480; e += 256) {
    int lr = e / 480, j = e - lr*480;
    int g = lr >> 3, cu = lr & 7;
    int r = g*400 + wg*8 + cu;
    float v;
    if (j < 400)      v = p.whh1[(size_t)r*400 + j];
    else if (j < 477) v = p.wih1[(size_t)r*80 + 3 + (j-400)];
    else              v = p.wih1[(size_t)r*80 + (j-477)];
    wgW[((size_t)(j>>2)*8 + cu)*16 + g*4 + (j&3)] = (_Float16)v;
  }
  for (int i = tid; i < 240; i += 256) wwinL[i] = p.wwin[(size_t)(i>>3)*400 + wg*8 + (i&7)];
  for (int i = tid; i < 640; i += 256) kapS[i] = p.pkap[i];
  float bsum[4];
#pragma unroll
  for (int g = 0; g < 4; ++g) bsum[g] = p.bih1[g*400+u] + p.bhh1[g*400+u];
  float creg[2];
  creg[0] = p.c0[(size_t)b0*H_ + u];
  creg[1] = p.c0[(size_t)(b0+1)*H_ + u];
  __syncthreads();

  for (int t = 0; t < T_; ++t) {
    float acc[2][4] = {{0,0,0,0},{0,0,0,0}};
    if (t > 0) wait_cnt(p.flags, 0, t-1, CNT0); else __syncthreads();
    const u32* h1p = p.fh1 + (size_t)(t-1)*64*200;   // valid t>0

    // -------- window phase (t>0): mix(t-1) -> kappa -> phi -> wv in LDS --------
    if (t > 0) {
      const float* gm = p.gmix + (size_t)(t-1)*2048;
#pragma unroll
      for (int it = 0; it < 8; ++it) {
        int i = tid + it*256; if (i >= 1920) break;
        int b = i/30, m = i - b*30;
        float e = __expf(gm[b*32 + m] + p.bwin[m]);
        mixT[b*30 + m] = e;
        if (m >= 20) kapS[b*10 + (m-20)] += e;
      }
      for (int i = tid; i < 4928; i += 256) wvs[i] = 0.f;
      __syncthreads();
#pragma unroll
      for (int it = 0; it < 13; ++it) {
        int i = tid + it*256; if (i >= 3200) break;
        int b = i/50, uu = i - b*50;
        const float fu = (float)uu;
        float s = 0.f;
#pragma unroll
        for (int k = 0; k < 10; ++k) {
          float df = kapS[b*10+k] - fu;
          s += mixT[b*30+k] * __expf(-mixT[b*30+10+k]*df*df);
        }
        s *= p.tmask[(size_t)b*U_ + uu];
        atomicAdd(&wvs[b*77 + p.text[(size_t)b*U_ + uu]], s);
      }
      __syncthreads();
    }
    // -------- wv+x pairs -> regs (t==0: from pwv) --------
    u32 wvp[10];
#pragma unroll
    for (int it = 0; it < 10; ++it) {
      int idx = tid + it*256; int b = idx/40, q = idx - b*40;
      u32 v;
      if (q < 38) {
        v = (t == 0) ? pkf(p.pwv[(size_t)b*V_ + 2*q], p.pwv[(size_t)b*V_ + 2*q + 1])
                     : pkf(wvs[b*77 + 2*q], wvs[b*77 + 2*q + 1]);
      } else if (q == 38) {
        float wv76 = (t == 0) ? p.pwv[(size_t)b*V_ + 76] : wvs[b*77 + 76];
        v = pkf(wv76, p.x[((size_t)b*T_ + t)*3 + 0]);
      } else {
        v = pkf(p.x[((size_t)b*T_ + t)*3 + 1], p.x[((size_t)b*T_ + t)*3 + 2]);
      }
      wvp[it] = v;
    }
    // ph0: rec pairs 0..79 -> panA (overwrites mixT overlay; wvs untouched)
    {
      u32 tmp[20];
#pragma unroll
      for (int it = 0; it < 20; ++it) {
        int idx = tid + it*256; int b = idx/80, q = idx - b*80;
        if (t == 0) { float2 f = *(const float2*)(p.h0 + (size_t)b*H_ + 2*q); tmp[it] = pkf(f.x, f.y); }
        else tmp[it] = h1p[b*200 + q];
      }
#pragma unroll
      for (int it = 0; it < 20; ++it) {
        int idx = tid + it*256; int b = idx/80, q = idx - b*80;
        ((u32*)panA)[b*90 + q] = tmp[it];
      }
    }
    __syncthreads();
    // ph1: rec pairs 80..159 -> panB || gemm0  (overwrites wvs overlay; wvp already in regs)
    {
      u32 tmp[20];
#pragma unroll
      for (int it = 0; it < 20; ++it) {
        int idx = tid + it*256; int b = idx/80, q = 80 + (idx - b*80);
        if (t == 0) { float2 f = *(const float2*)(p.h0 + (size_t)b*H_ + 2*q); tmp[it] = pkf(f.x, f.y); }
        else tmp[it] = h1p[b*200 + q];
      }
      gemm_phase<160>(panA, SW1, wgW, cg, 0, b0, acc);
#pragma unroll
      for (int it = 0; it < 20; ++it) {
        int idx = tid + it*256; int b = idx/80, q = idx - b*80;
        ((u32*)panB)[b*90 + q] = tmp[it];
      }
    }
    __syncthreads();
    // ph2: rec pairs 160..199 -> panA[0..39], wvp -> panA[40..79] || gemm1
    {
      u32 tmp[10];
#pragma unroll
      for (int it = 0; it < 10; ++it) {
        int idx = tid + it*256; int b = idx/40, q = idx - b*40;
        if (t == 0) { float2 f = *(const float2*)(p.h0 + (size_t)b*H_ + 2*(160+q)); tmp[it] = pkf(f.x, f.y); }
        else tmp[it] = h1p[b*200 + 160 + q];
      }
      gemm_phase<160>(panB, SW1, wgW, cg, 160, b0, acc);
#pragma unroll
      for (int it = 0; it < 10; ++it) {
        int idx = tid + it*256; int b = idx/40, q = idx - b*40;
        ((u32*)panA)[b*90 + q] = tmp[it];
        ((u32*)panA)[b*90 + 40 + q] = wvp[it];
      }
    }
    __syncthreads();
    // gemm2: dims 320..479 (rec tail + wv + x), same accumulation order as before
    gemm_phase<160>(panA, SW1, wgW, cg, 320, b0, acc);

    float hn[2];
#pragma unroll
    for (int r = 0; r < 2; ++r) {
      float gi = acc[r][0]+bsum[0], gf = acc[r][1]+bsum[1];
      float gg = acc[r][2]+bsum[2], go = acc[r][3]+bsum[3];
      float cn = sigm(gf)*creg[r] + sigm(gi)*tanhf(gg);
      creg[r] = cn;
      hn[r] = sigm(go)*tanhf(cn);
    }
    {
      float h0p = __shfl_xor(hn[0], 1, 64);
      float h1x = __shfl_xor(hn[1], 1, 64);
      if ((cg & 1) == 0) {
        const int pi = wg*4 + (cg >> 1);
        stc_u(p.fh1 + ((size_t)t*64 + b0)*200 + pi, pkf(hn[0], h0p));
        stc_u(p.fh1 + ((size_t)t*64 + b0+1)*200 + pi, pkf(hn[1], h1x));
      }
    }
    hsl[b0*8 + cg] = hn[0];
    hsl[(b0+1)*8 + cg] = hn[1];
    __syncthreads();
    // mix partials for this block's 8 dims -> gmix[t]
    {
      float* gm = p.gmix + (size_t)t*2048;
#pragma unroll
      for (int it = 0; it < 8; ++it) {
        int i = tid + it*256; if (i >= 1920) break;
        int b = i/30, m = i - b*30;
        float s = 0.f;
#pragma unroll
        for (int j = 0; j < 8; ++j) s += hsl[b*8+j] * wwinL[m*8+j];
        gaddf(gm + b*32 + m, s);
      }
    }
    __syncthreads();   // drains fh1 stores + gmix atomics
    add_cnt(p.flags, 0, t);
  }
}

// ================= PA: gmix -> outputs (out_wv, out_kap, fwv) =================
__device__ void pa_role(const P& p, int pa, char* smem) {
  const int tid = threadIdx.x;
  const int b0p = pa*4;
  float* mixL = (float*)smem;            // [4][30]
  float* kapP = (float*)(smem + 512);    // [4][10]
  float* wvs  = (float*)(smem + 768);    // [4][77]
  for (int i = tid; i < 40; i += 256) kapP[i] = p.pkap[(size_t)b0p*10 + i];
  __syncthreads();

  for (int t = 0; t < T_; ++t) {
    wait_cnt(p.flags, 0, t, CNT0);
    for (int i = tid; i < 308; i += 256) wvs[i] = 0.f;
    if (tid < 120) {
      int bl = tid/30, m = tid - bl*30;
      float e = __expf(p.gmix[(size_t)t*2048 + (b0p+bl)*32 + m] + p.bwin[m]);
      mixL[tid] = e;
      if (m >= 20) kapP[bl*10 + (m-20)] += e;
    }
    __syncthreads();
    if (tid < 200) {
      int bl = tid/50, uu = tid - bl*50;
      const float fu = (float)uu;
      float s = 0.f;
#pragma unroll
      for (int k = 0; k < 10; ++k) {
        float df = kapP[bl*10+k] - fu;
        s += mixL[bl*30+k] * __expf(-mixL[bl*30+10+k]*df*df);
      }
      s *= p.tmask[(size_t)(b0p+bl)*U_ + uu];
      atomicAdd(&wvs[bl*77 + p.text[(size_t)(b0p+bl)*U_ + uu]], s);
    }
    __syncthreads();
    for (int i = tid; i < 308; i += 256) {
      int bl = i / 77, v = i - (i/77)*77;
      p.out_wv[((size_t)(b0p+bl)*T_ + t)*V_ + v] = wvs[i];
    }
    if (t == T_-1) {
      for (int i = tid; i < 40; i += 256)
        p.out_kap[(size_t)b0p*10 + i] = kapP[i];
    }
    for (int i = tid; i < 160; i += 256) {
      int bl = i / 40, pr = i - (i/40)*40;
      int b = b0p + bl;
      float f0, f1;
      if (pr < 38)       { f0 = wvs[bl*77 + 2*pr]; f1 = wvs[bl*77 + 2*pr + 1]; }
      else if (pr == 38) { f0 = wvs[bl*77 + 76];   f1 = p.x[((size_t)b*T_ + t)*3 + 0]; }
      else               { f0 = p.x[((size_t)b*T_ + t)*3 + 1]; f1 = p.x[((size_t)b*T_ + t)*3 + 2]; }
      stc_u(p.fwv + ((size_t)t*64 + b)*40 + pr, pkf(f0, f1));
    }
    __syncthreads();
    add_cnt(p.flags, 1, t);
  }
}

// ================= L2/L3 =================
template <int L>
__device__ void lstm_role(const P& p, int wg, char* smem) {
  const int tid = threadIdx.x, cg = tid & 7, tb = tid >> 3;
  const int u = wg*8 + cg, b0 = tb*2;
  constexpr int STG = (L==2) ? 2 : 3;
  _Float16* wgW = ((L==2) ? p.w2f : p.w3f) + (size_t)wg * W2WG;
  const float* wih = (L==2) ? p.wih2 : p.wih3;
  const float* whh = (L==2) ? p.whh2 : p.whh3;
  const float* bih = (L==2) ? p.bih2 : p.bih3;
  const float* bhh = (L==2) ? p.bhh2 : p.bhh3;
  const u32* hin = (L==2) ? p.fh1 : p.fh2;
  u32* rec = (L==2) ? p.fh2 : p.fh3;
  _Float16* panA = (_Float16*)smem;
  _Float16* panB = panA + 64*SW2;

  // K-order dims: [wv 0..76 | x 77..79 | hin 80..479 | hrec 480..879]
  for (int e = tid; e < 32*880; e += 256) {
    int lr = e / 880, j = e - lr*880;
    int g = lr >> 3, cu = lr & 7;
    int r = g*400 + wg*8 + cu;
    float v;
    if (j < 77)       v = wih[(size_t)r*480 + 403 + j];
    else if (j < 80)  v = wih[(size_t)r*480 + (j-77)];
    else if (j < 480) v = wih[(size_t)r*480 + 3 + (j-80)];
    else              v = whh[(size_t)r*400 + (j-480)];
    wgW[((size_t)(j>>2)*8 + cu)*16 + g*4 + (j&3)] = (_Float16)v;
  }
  float bsum[4];
#pragma unroll
  for (int g = 0; g < 4; ++g) bsum[g] = bih[g*400+u] + bhh[g*400+u];
  float creg[2];
  creg[0] = p.c0[(size_t)(L-1)*B_*H_ + (size_t)b0*H_ + u];
  creg[1] = p.c0[(size_t)(L-1)*B_*H_ + (size_t)(b0+1)*H_ + u];
  __syncthreads();

  for (int t = 0; t < T_; ++t) {
    float acc[2][4] = {{0,0,0,0},{0,0,0,0}};
    // combined: upstream(t) AND own rec(t-1) (early-satisfied in steady state)
    if (L == 2) wait_cnt2(p.flags, 1, t, CNT1, STG, CNT2);
    else        wait_cnt2(p.flags, 2, t, CNT2, STG, CNT2);
    const u32* fwvt = p.fwv + (size_t)t*64*40;
    const u32* hint = hin + (size_t)t*64*200;
    const u32* rect = rec + (size_t)(t-1)*64*200;  // valid t>0
    const float* h0f = p.h0 + (size_t)(L-1)*B_*H_;
    // ph0: pairs 0..109 = [wv+x 40 | hin 0..69]
    {
      u32 tmp[28];
#pragma unroll
      for (int it = 0; it < 28; ++it) {
        int idx = tid + it*256; if (idx >= 7040) break;
        int b = idx/110, pl = idx - b*110;
        tmp[it] = (pl < 40) ? fwvt[b*40 + pl] : hint[b*200 + (pl-40)];
      }
#pragma unroll
      for (int it = 0; it < 28; ++it) {
        int idx = tid + it*256; if (idx >= 7040) break;
        int b = idx/110, pl = idx - b*110;
        ((u32*)panA)[b*114 + pl] = tmp[it];
      }
    }
    __syncthreads();
    // ph1: pairs 110..219 = hin 70..179 || gemm0
    {
      u32 tmp[28];
#pragma unroll
      for (int it = 0; it < 28; ++it) {
        int idx = tid + it*256; if (idx >= 7040) break;
        int b = idx/110, pl = idx - b*110;
        tmp[it] = hint[b*200 + 70 + pl];
      }
      gemm_phase<220>(panA, SW2, wgW, cg, 0, b0, acc);
#pragma unroll
      for (int it = 0; it < 28; ++it) {
        int idx = tid + it*256; if (idx >= 7040) break;
        int b = idx/110, pl = idx - b*110;
        ((u32*)panB)[b*114 + pl] = tmp[it];
      }
    }
    __syncthreads();
    // ph2: pairs 220..329 = [hin 180..199 | rec 0..89] || gemm1
    {
      u32 tmp[28];
#pragma unroll
      for (int it = 0; it < 28; ++it) {
        int idx = tid + it*256; if (idx >= 7040) break;
        int b = idx/110, pl = idx - b*110;
        u32 v;
        if (pl < 20) v = hint[b*200 + 180 + pl];
        else if (t == 0) { float2 f = *(const float2*)(h0f + (size_t)b*H_ + 2*(pl-20)); v = pkf(f.x, f.y); }
        else v = rect[b*200 + (pl-20)];
        tmp[it] = v;
      }
      gemm_phase<220>(panB, SW2, wgW, cg, 220, b0, acc);
#pragma unroll
      for (int it = 0; it < 28; ++it) {
        int idx = tid + it*256; if (idx >= 7040) break;
        int b = idx/110, pl = idx - b*110;
        ((u32*)panA)[b*114 + pl] = tmp[it];
      }
    }
    __syncthreads();
    // ph3: pairs 330..439 = rec 90..199 || gemm2
    {
      u32 tmp[28];
#pragma unroll
      for (int it = 0; it < 28; ++it) {
        int idx = tid + it*256; if (idx >= 7040) break;
        int b = idx/110, pl = idx - b*110;
        u32 v;
        if (t == 0) { float2 f = *(const float2*)(h0f + (size_t)b*H_ + 2*(90+pl)); v = pkf(f.x, f.y); }
        else v = rect[b*200 + 90 + pl];
        tmp[it] = v;
      }
      gemm_phase<220>(panA, SW2, wgW, cg, 440, b0, acc);
#pragma unroll
      for (int it = 0; it < 28; ++it) {
        int idx = tid + it*256; if (idx >= 7040) break;
        int b = idx/110, pl = idx - b*110;
        ((u32*)panB)[b*114 + pl] = tmp[it];
      }
    }
    __syncthreads();
    gemm_phase<220>(panB, SW2, wgW, cg, 660, b0, acc);

    float hn[2];
#pragma unroll
    for (int r = 0; r < 2; ++r) {
      float gi = acc[r][0]+bsum[0], gf = acc[r][1]+bsum[1];
      float gg = acc[r][2]+bsum[2], go = acc[r][3]+bsum[3];
      float cn = sigm(gf)*creg[r] + sigm(gi)*tanhf(gg);
      creg[r] = cn;
      hn[r] = sigm(go)*tanhf(cn);
    }
    {
      float h0p = __shfl_xor(hn[0], 1, 64);
      float h1x = __shfl_xor(hn[1], 1, 64);
      if ((cg & 1) == 0) {
        const int pi = wg*4 + (cg >> 1);
        stc_u(rec + ((size_t)t*64 + b0)*200 + pi, pkf(hn[0], h0p));
        stc_u(rec + ((size_t)t*64 + b0+1)*200 + pi, pkf(hn[1], h1x));
      }
    }
    __syncthreads();
    add_cnt(p.flags, STG, t);
  }
}

// ================= OUT =================
__device__ void out_role(const P& p, int g, char* smem) {
  const int tid = threadIdx.x;
  const int cg = tid & 31, bg = tid >> 5;
  const int c0 = cg*4;
  _Float16* pan = (_Float16*)smem;
  _Float16* wofg = p.wof + (size_t)g*WOWG;
  for (int e = tid; e < 300*32*16; e += 256) {
    int kk = e >> 9, rem = e & 511;
    int cgi = rem >> 4, j4 = rem & 15;
    int j = j4 >> 2, kc = j4 & 3;
    int c = cgi*4 + j; if (c > 120) c = 120;
    wofg[e] = (_Float16)p.wout[(size_t)c*1200 + kk*4 + kc];
  }
  float bo[4];
#pragma unroll
  for (int j = 0; j < 4; ++j) {
    int c = c0 + j; if (c > 120) c = 120;
    bo[j] = p.bout[c];
  }
  __syncthreads();

  for (int t = g; t < T_; t += GOUT) {
    wait_cnt(p.flags, 3, t, CNT3);
    float acc[8][4];
#pragma unroll
    for (int r = 0; r < 8; ++r)
#pragma unroll
      for (int j = 0; j < 4; ++j) acc[r][j] = 0.f;

    for (int ph = 0; ph < 5; ++ph) {
      for (int idx = tid; idx < 7680; idx += 256) {
        int b = idx / 120, pl = idx - b*120;
        int Pp = ph*120 + pl;
        u32 pv;
        if (Pp < 200)      pv = p.fh1[((size_t)t*64 + b)*200 + Pp];
        else if (Pp < 400) pv = p.fh2[((size_t)t*64 + b)*200 + (Pp-200)];
        else               pv = p.fh3[((size_t)t*64 + b)*200 + (Pp-400)];
        ((u32*)pan)[b*122 + pl] = pv;
      }
      __syncthreads();
      const _Float16* wp = wofg + ((size_t)(ph*60)*32 + cg)*16;
#pragma unroll 3
      for (int k = 0; k < 240; k += 4) {
        h4 wa = *(const h4*)(wp);
        h4 wb = *(const h4*)(wp+4);
        h4 wc = *(const h4*)(wp+8);
        h4 wd = *(const h4*)(wp+12);
        wp += 512;
#pragma unroll
        for (int r = 0; r < 8; ++r) {
          h4 a = *(const h4*)(pan + (bg*8+r)*SWO + k);
          h2 al = lo4(a), ah = hi4(a);
          acc[r][0] = dot2(al, lo4(wa), acc[r][0]); acc[r][0] = dot2(ah, hi4(wa), acc[r][0]);
          acc[r][1] = dot2(al, lo4(wb), acc[r][1]); acc[r][1] = dot2(ah, hi4(wb), acc[r][1]);
          acc[r][2] = dot2(al, lo4(wc), acc[r][2]); acc[r][2] = dot2(ah, hi4(wc), acc[r][2]);
          acc[r][3] = dot2(al, lo4(wd), acc[r][3]); acc[r][3] = dot2(ah, hi4(wd), acc[r][3]);
        }
      }
      __syncthreads();
    }
#pragma unroll
    for (int r = 0; r < 8; ++r)
#pragma unroll
      for (int j = 0; j < 4; ++j) {
        int c = c0 + j;
        if (c < 121)
          p.out_y[((size_t)(bg*8+r)*T_ + t)*OUT_ + c] = acc[r][j] + bo[j];
      }
    __syncthreads();
  }
}

__global__ __launch_bounds__(256) void hw_pipeline(P p) {
  __shared__ __align__(16) char smem_raw[SMEM_BYTES];
  const int bid = blockIdx.x;
  if (bid < G1) lstm1_role(p, bid, smem_raw);
  else if (bid < G1+GPA) pa_role(p, bid - G1, smem_raw);
  else if (bid < G1+GPA+G2) lstm_role<2>(p, bid - G1 - GPA, smem_raw);
  else if (bid < G1+GPA+G2+G3) lstm_role<3>(p, bid - G1 - GPA - G2, smem_raw);
  else out_role(p, bid - G1 - GPA - G2 - G3, smem_raw);
}

extern "C" void kernel_launch(void* const* d_in, const int* in_sizes, int n_in,
                              void* d_out, int out_size, void* d_ws, size_t ws_size,
                              hipStream_t stream) {
  (void)in_sizes; (void)n_in; (void)out_size; (void)ws_size;
  P p;
  p.x = (const float*)d_in[0];
  p.text = (const int*)d_in[1];
  p.tmask = (const float*)d_in[2];
  p.h0 = (const float*)d_in[3];
  p.c0 = (const float*)d_in[4];
  p.pwv = (const float*)d_in[5];
  p.pkap = (const float*)d_in[6];
  p.wih1 = (const float*)d_in[7];  p.whh1 = (const float*)d_in[8];
  p.bih1 = (const float*)d_in[9];  p.bhh1 = (const float*)d_in[10];
  p.wih2 = (const float*)d_in[11]; p.whh2 = (const float*)d_in[12];
  p.bih2 = (const float*)d_in[13]; p.bhh2 = (const float*)d_in[14];
  p.wih3 = (const float*)d_in[15]; p.whh3 = (const float*)d_in[16];
  p.bih3 = (const float*)d_in[17]; p.bhh3 = (const float*)d_in[18];
  p.wwin = (const float*)d_in[19]; p.bwin = (const float*)d_in[20];
  p.wout = (const float*)d_in[21]; p.bout = (const float*)d_in[22];
  float* out = (float*)d_out;
  p.out_y  = out;
  p.out_wv = out + (size_t)B_*T_*OUT_;
  p.out_kap = p.out_wv + (size_t)B_*T_*V_;
  char* ws = (char*)d_ws;
  p.flags = (u32*)(ws + FLAGS_B);
  p.w1f = (_Float16*)(ws + W1F_B);
  p.w2f = (_Float16*)(ws + W2F_B);
  p.w3f = (_Float16*)(ws + W3F_B);
  p.wof = (_Float16*)(ws + WOF_B);
  p.gmix = (float*)(ws + GMIX_B);
  p.fwv = (u32*)(ws + FWV_B);
  p.fh1 = (u32*)(ws + FH1_B);
  p.fh2 = (u32*)(ws + FH2_B);
  p.fh3 = (u32*)(ws + FH3_B);
  (void)hipMemsetAsync(ws + FLAGS_B, 0, FLAGS_SZ, stream);
  (void)hipMemsetAsync(ws + GMIX_B, 0, GMIX_SZ, stream);
  hipLaunchKernelGGL(hw_pipeline, dim3(NBLK), dim3(256), 0, stream, p);
}

// Round 6
// 15505.457 us; speedup vs baseline: 1.7042x; 1.7042x over previous
//
#include <hip/hip_runtime.h>
#include <cstdint>
#include <cstddef>
#include <cstring>

using u32 = unsigned int;
typedef _Float16 h2 __attribute__((ext_vector_type(2)));
typedef _Float16 h4 __attribute__((ext_vector_type(4)));
typedef _Float16 h8 __attribute__((ext_vector_type(8)));
typedef float f32x4 __attribute__((ext_vector_type(4)));

constexpr int B_=64, T_=600, U_=50, V_=77, H_=400, OUT_=121;
constexpr int G1=50, GPA=16, G2=50, G3=50, GOUT=8;
constexpr int NBLK = G1+GPA+G2+G3+GOUT; // 174
constexpr u32 CNT0=50, CNT1=16, CNT2=50, CNT3=50;

// ---- ws byte offsets ----
constexpr size_t FLAGS_B = 0;                        // [stage4][t600] 64B counter slots
constexpr size_t FLAGS_SZ = 4ull*600*64;             // 153,600
// MFMA weight packs: [ks][row32][q4][i8] f16, row = unit_local*4 + gate
constexpr size_t W1WG   = 15ull*32*4*8;              // 15360 f16 (K=480)
constexpr size_t W1F_B  = FLAGS_SZ;
constexpr size_t W2WG   = 28ull*32*4*8;              // 28672 f16 (K=896 padded)
constexpr size_t W2F_B  = W1F_B + 50ull*W1WG*2;      // 1,689,600
constexpr size_t W3F_B  = W2F_B + 50ull*W2WG*2;      // 4,556,800
constexpr size_t WOWG   = 300ull*32*16;
constexpr size_t WOF_B  = W3F_B + 50ull*W2WG*2;      // 7,424,000
constexpr size_t WWFWG  = 200ull*32;                 // u32
constexpr size_t WWF_B  = WOF_B + 8ull*WOWG*2;       // 9,881,600
// write-once, t-indexed inter-stage buffers (consumers: plain CACHED loads)
constexpr size_t FWV_B  = WWF_B + 16ull*WWFWG*4;     // u32 [600][64][40]
constexpr size_t FH1_B  = FWV_B + 600ull*64*40*4;    // u32 [600][64][200]
constexpr size_t FH2_B  = FH1_B + 600ull*64*200*4;
constexpr size_t FH3_B  = FH2_B + 600ull*64*200*4;
// total ~108.6 MB

// LDS strides (f16 units) — 16B-aligned rows for ds_read_b128 B-fragments
constexpr int SW1 = 184;   // L1 panels (160 dims used, 92 u32 pairs)
constexpr int SW2 = 232;   // L2/L3 panels (224 dims used, 116 u32 pairs)
constexpr int SWO = 244;   // OUT (240 dims)
constexpr int SMEM_BYTES = 59392;   // L2 panels: 2*64*232*2

struct P {
  const float *x, *tmask, *h0, *c0, *pwv, *pkap;
  const int *text;
  const float *wih1,*whh1,*bih1,*bhh1;
  const float *wih2,*whh2,*bih2,*bhh2;
  const float *wih3,*whh3,*bih3,*bhh3;
  const float *wwin,*bwin,*wout,*bout;
  float *out_y,*out_wv,*out_kap;
  _Float16 *w1f,*w2f,*w3f,*wof;
  u32 *wwf;
  u32 *fwv,*fh1,*fh2,*fh3;
  u32 *flags;
};

__device__ __forceinline__ u32 ldc_u(const u32* p) {
  return __hip_atomic_load((u32*)p, __ATOMIC_RELAXED, __HIP_MEMORY_SCOPE_AGENT);
}
__device__ __forceinline__ void stc_u(u32* p, u32 v) {
  __hip_atomic_store(p, v, __ATOMIC_RELAXED, __HIP_MEMORY_SCOPE_AGENT);
}
__device__ __forceinline__ float sigm(float x) { return 1.f/(1.f+__expf(-x)); }
__device__ __forceinline__ h2 pk16(float a, float b) {
  auto t = __builtin_amdgcn_cvt_pkrtz(a, b);
  h2 r; memcpy(&r, &t, 4); return r;
}
__device__ __forceinline__ u32 h2u(h2 v) { u32 r; memcpy(&r, &v, 4); return r; }
__device__ __forceinline__ h2 u2h(u32 v) { h2 r; memcpy(&r, &v, 4); return r; }
__device__ __forceinline__ u32 pkf(float a, float b) { return h2u(pk16(a, b)); }
__device__ __forceinline__ float dot2(h2 a, h2 b, float c) { return __builtin_amdgcn_fdot2(a, b, c, false); }
__device__ __forceinline__ h2 lo4(h4 v) { return __builtin_shufflevector(v, v, 0, 1); }
__device__ __forceinline__ h2 hi4(h4 v) { return __builtin_shufflevector(v, v, 2, 3); }

// ---- single-counter barriers ----
__device__ __forceinline__ void wait_cnt(u32* cnt, int stage, int t, u32 target) {
  if (threadIdx.x == 0) {
    const u32* s = cnt + ((size_t)stage*600 + t)*16;   // 64B slot
    while (ldc_u(s) < target) {}
  }
  __syncthreads();
}
__device__ __forceinline__ void add_cnt(u32* cnt, int stage, int t) {
  if (threadIdx.x == 0)
    (void)__hip_atomic_fetch_add(cnt + ((size_t)stage*600 + t)*16, 1u,
                                 __ATOMIC_RELAXED, __HIP_MEMORY_SCOPE_AGENT);
}

// ---- MFMA chunk: wave w computes 2 C-tiles (16 rows x 16 batches each) over KS k-steps
// pan: LDS panel [batch64][SWf f16], k-contiguous per batch row
// WA:  weight pack base for this chunk: [ks][row32][q4][i8] f16
__device__ __forceinline__ void mfma_chunk5(const _Float16* pan, int SWf, const _Float16* WA,
                                            int w, int l, f32x4& acc0, f32x4& acc1) {
  const _Float16* bp0 = pan + ((w>>1)*32 + (l&15))*SWf + (l>>4)*8;
  const _Float16* bp1 = bp0 + 16*SWf;
  const _Float16* ap  = WA + (((16*(w&1) + (l&15))*4) + (l>>4))*8;
#pragma unroll
  for (int ks = 0; ks < 5; ++ks) {
    h8 a  = *(const h8*)(ap  + ks*1024);
    h8 b0 = *(const h8*)(bp0 + ks*32);
    h8 b1 = *(const h8*)(bp1 + ks*32);
    acc0 = __builtin_amdgcn_mfma_f32_16x16x32_f16(a, b0, acc0, 0, 0, 0);
    acc1 = __builtin_amdgcn_mfma_f32_16x16x32_f16(a, b1, acc1, 0, 0, 0);
  }
}
__device__ __forceinline__ void mfma_chunk7(const _Float16* pan, int SWf, const _Float16* WA,
                                            int w, int l, f32x4& acc0, f32x4& acc1) {
  const _Float16* bp0 = pan + ((w>>1)*32 + (l&15))*SWf + (l>>4)*8;
  const _Float16* bp1 = bp0 + 16*SWf;
  const _Float16* ap  = WA + (((16*(w&1) + (l&15))*4) + (l>>4))*8;
#pragma unroll
  for (int ks = 0; ks < 7; ++ks) {
    h8 a  = *(const h8*)(ap  + ks*1024);
    h8 b0 = *(const h8*)(bp0 + ks*32);
    h8 b1 = *(const h8*)(bp1 + ks*32);
    acc0 = __builtin_amdgcn_mfma_f32_16x16x32_f16(a, b0, acc0, 0, 0, 0);
    acc1 = __builtin_amdgcn_mfma_f32_16x16x32_f16(a, b1, acc1, 0, 0, 0);
  }
}

// ================= L1 =================
__device__ void lstm1_role(const P& p, int wg, char* smem) {
  const int tid = threadIdx.x;
  const int w = tid >> 6, l = tid & 63;
  const int ul = (w&1)*4 + (l>>4);           // unit_local 0..7
  const int u  = wg*8 + ul;
  const int bA = (w>>1)*32 + (l&15), bB = bA + 16;
  _Float16* panA = (_Float16*)smem;
  _Float16* panB = panA + 64*SW1;
  _Float16* wgW = p.w1f + (size_t)wg * W1WG;
  // prepack [ks15][row32][q4][i8]; row = cu*4+g; K-order [rec400 | wv77 | x3]
  for (int e = tid; e < 15360; e += 256) {
    int i = e & 7, q = (e>>3)&3, row = (e>>5)&31, ks = e>>10;
    int k = ks*32 + q*8 + i;
    int cu = row>>2, g = row&3;
    int r = g*400 + wg*8 + cu;
    float v;
    if (k < 400)      v = p.whh1[(size_t)r*400 + k];
    else if (k < 477) v = p.wih1[(size_t)r*80 + 3 + (k-400)];
    else              v = p.wih1[(size_t)r*80 + (k-477)];
    wgW[e] = (_Float16)v;
  }
  float bsum[4];
#pragma unroll
  for (int g = 0; g < 4; ++g) bsum[g] = p.bih1[g*400+u] + p.bhh1[g*400+u];
  float creg[2];
  creg[0] = p.c0[(size_t)bA*H_ + u];
  creg[1] = p.c0[(size_t)bB*H_ + u];
  __syncthreads();

  for (int t = 0; t < T_; ++t) {
    f32x4 acc0 = {0.f,0.f,0.f,0.f}, acc1 = {0.f,0.f,0.f,0.f};
    if (t > 0) wait_cnt(p.flags, 0, t-1, CNT0); else __syncthreads();
    const u32* h1p = p.fh1 + (size_t)(t-1)*64*200;   // valid t>0
    // S0: rec pairs 0..79 -> panA
    {
      u32 tmp[20];
#pragma unroll
      for (int it = 0; it < 20; ++it) {
        int idx = tid + it*256; int b = idx/80, q = idx - b*80;
        if (t == 0) { float2 f = *(const float2*)(p.h0 + (size_t)b*H_ + 2*q); tmp[it] = pkf(f.x, f.y); }
        else tmp[it] = h1p[b*200 + q];
      }
#pragma unroll
      for (int it = 0; it < 20; ++it) {
        int idx = tid + it*256; int b = idx/80, q = idx - b*80;
        ((u32*)panA)[b*92 + q] = tmp[it];
      }
    }
    __syncthreads();
    // S1: rec pairs 80..159 -> panB || M0(panA: dims 0..159)
    {
      u32 tmp[20];
#pragma unroll
      for (int it = 0; it < 20; ++it) {
        int idx = tid + it*256; int b = idx/80, q = 80 + (idx - b*80);
        if (t == 0) { float2 f = *(const float2*)(p.h0 + (size_t)b*H_ + 2*q); tmp[it] = pkf(f.x, f.y); }
        else tmp[it] = h1p[b*200 + q];
      }
      mfma_chunk5(panA, SW1, wgW, w, l, acc0, acc1);
#pragma unroll
      for (int it = 0; it < 20; ++it) {
        int idx = tid + it*256; int b = idx/80, q = idx - b*80;
        ((u32*)panB)[b*92 + q] = tmp[it];
      }
    }
    __syncthreads();
    // S2a: rec pairs 160..199 -> panA[0..39] || M1(panB: dims 160..319)
    {
      u32 tmp[10];
#pragma unroll
      for (int it = 0; it < 10; ++it) {
        int idx = tid + it*256; int b = idx/40, q = idx - b*40;
        if (t == 0) { float2 f = *(const float2*)(p.h0 + (size_t)b*H_ + 2*(160+q)); tmp[it] = pkf(f.x, f.y); }
        else tmp[it] = h1p[b*200 + 160 + q];
      }
      mfma_chunk5(panB, SW1, wgW + 5*1024, w, l, acc0, acc1);
#pragma unroll
      for (int it = 0; it < 10; ++it) {
        int idx = tid + it*256; int b = idx/40, q = idx - b*40;
        ((u32*)panA)[b*92 + q] = tmp[it];
      }
    }
    // wait for wv(t-1) only now (PA is fast; usually satisfied)
    if (t > 0) wait_cnt(p.flags, 1, t-1, CNT1); else __syncthreads();
    // S2b: wv+x pairs -> panA[40..79]
    {
      u32 tmp[10];
#pragma unroll
      for (int it = 0; it < 10; ++it) {
        int idx = tid + it*256; int b = idx/40, q = idx - b*40;
        u32 v;
        if (q < 38) {
          if (t == 0) v = pkf(p.pwv[(size_t)b*V_ + 2*q], p.pwv[(size_t)b*V_ + 2*q + 1]);
          else v = p.fwv[((size_t)(t-1)*64 + b)*40 + q];
        } else if (q == 38) {
          float wv76 = (t == 0) ? p.pwv[(size_t)b*V_ + 76]
                                : (float)u2h(p.fwv[((size_t)(t-1)*64 + b)*40 + 38]).x;
          v = pkf(wv76, p.x[((size_t)b*T_ + t)*3 + 0]);
        } else {
          v = pkf(p.x[((size_t)b*T_ + t)*3 + 1], p.x[((size_t)b*T_ + t)*3 + 2]);
        }
        tmp[it] = v;
      }
#pragma unroll
      for (int it = 0; it < 10; ++it) {
        int idx = tid + it*256; int b = idx/40, q = idx - b*40;
        ((u32*)panA)[b*92 + 40 + q] = tmp[it];
      }
    }
    __syncthreads();
    // M2(panA: dims 320..479)
    mfma_chunk5(panA, SW1, wgW + 10*1024, w, l, acc0, acc1);

    // activation: lane's acc[j] = gate j of (u, bA/bB)
    float hA, hB;
    {
      float cn = sigm(acc0[1]+bsum[1])*creg[0] + sigm(acc0[0]+bsum[0])*tanhf(acc0[2]+bsum[2]);
      creg[0] = cn; hA = sigm(acc0[3]+bsum[3])*tanhf(cn);
      float cn2 = sigm(acc1[1]+bsum[1])*creg[1] + sigm(acc1[0]+bsum[0])*tanhf(acc1[2]+bsum[2]);
      creg[1] = cn2; hB = sigm(acc1[3]+bsum[3])*tanhf(cn2);
    }
    {
      float hAp = __shfl_xor(hA, 16, 64);
      float hBp = __shfl_xor(hB, 16, 64);
      if (((l>>4) & 1) == 0) {
        const int pi = wg*4 + (ul>>1);
        stc_u(p.fh1 + ((size_t)t*64 + bA)*200 + pi, pkf(hA, hAp));
        stc_u(p.fh1 + ((size_t)t*64 + bB)*200 + pi, pkf(hB, hBp));
      }
    }
    __syncthreads();
    add_cnt(p.flags, 0, t);
  }
}

// ================= PA (attention) — 16 blocks x 4 batches =================
__device__ void pa_role(const P& p, int pa, char* smem) {
  const int tid = threadIdx.x;
  const int b0p = pa*4;
  u32* hsm    = (u32*)smem;                 // [4][200]
  float* mixP = (float*)(smem + 3200);      // 240
  float* mixL = (float*)(smem + 4160);      // 120
  float* kapL = (float*)(smem + 4640);      // 40
  float* wvs  = (float*)(smem + 4800);      // 308
  int* textL  = (int*)(smem + 6032);        // 200
  u32* wwf = p.wwf + (size_t)pa * WWFWG;
  for (int e = tid; e < 200*30; e += 256) {
    int kk = e / 30, m = e - (e/30)*30;
    wwf[(size_t)kk*32 + m] = pkf(p.wwin[(size_t)m*400 + 2*kk], p.wwin[(size_t)m*400 + 2*kk + 1]);
  }
  for (int i = tid; i < 200; i += 256)
    textL[i] = p.text[(size_t)(b0p + i/50)*U_ + (i - (i/50)*50)];
  float kap_reg = 0.f;
  if (tid < 120 && (tid % 30) >= 20)
    kap_reg = p.pkap[(size_t)(b0p + tid/30)*10 + (tid % 30 - 20)];
  __syncthreads();

  for (int t = 0; t < T_; ++t) {
    wait_cnt(p.flags, 0, t, CNT0);
    for (int e = tid; e < 800; e += 256) {
      int bl = e / 200, q = e - bl*200;
      hsm[e] = p.fh1[((size_t)t*64 + b0p + bl)*200 + q];
    }
    for (int i = tid; i < 308; i += 256) wvs[i] = 0.f;
    __syncthreads();
    if (tid < 240) {
      int pp = tid >> 1, h = tid & 1;
      int bl = pp / 30, m = pp - bl*30;
      const u32* hp = hsm + bl*200 + h*100;
      const u32* wp = wwf + (size_t)(h*100)*32 + m;
      float d0=0.f, d1=0.f, d2=0.f, d3=0.f;
#pragma unroll 4
      for (int kk = 0; kk < 100; kk += 4) {
        d0 = dot2(u2h(hp[kk]),   u2h(wp[(size_t)kk*32]),     d0);
        d1 = dot2(u2h(hp[kk+1]), u2h(wp[(size_t)(kk+1)*32]), d1);
        d2 = dot2(u2h(hp[kk+2]), u2h(wp[(size_t)(kk+2)*32]), d2);
        d3 = dot2(u2h(hp[kk+3]), u2h(wp[(size_t)(kk+3)*32]), d3);
      }
      mixP[tid] = (d0+d1)+(d2+d3);
    }
    __syncthreads();
    if (tid < 120) {
      int bl = tid / 30, m = tid - bl*30;
      float v = __expf(mixP[2*tid] + mixP[2*tid+1] + p.bwin[m]);
      mixL[tid] = v;
      if (m >= 20) {
        kap_reg += v;
        kapL[bl*10 + (m-20)] = kap_reg;
        if (t == T_-1) p.out_kap[(size_t)(b0p+bl)*10 + (m-20)] = kap_reg;
      }
    }
    __syncthreads();
    if (tid < 200) {
      int bl = tid / 50, uu = tid - bl*50;
      const float fu = (float)uu;
      float s = 0.f;
#pragma unroll
      for (int k = 0; k < 10; ++k) {
        float df = kapL[bl*10+k] - fu;
        s += mixL[bl*30+k] * __expf(-mixL[bl*30+10+k]*df*df);
      }
      s *= p.tmask[(size_t)(b0p+bl)*U_ + uu];
      atomicAdd(&wvs[bl*77 + textL[tid]], s);
    }
    __syncthreads();
    for (int i = tid; i < 308; i += 256) {
      int bl = i / 77, v = i - (i/77)*77;
      p.out_wv[((size_t)(b0p+bl)*T_ + t)*V_ + v] = wvs[i];
    }
    for (int i = tid; i < 160; i += 256) {
      int bl = i / 40, pr = i - (i/40)*40;
      int b = b0p + bl;
      float f0, f1;
      if (pr < 38)       { f0 = wvs[bl*77 + 2*pr]; f1 = wvs[bl*77 + 2*pr + 1]; }
      else if (pr == 38) { f0 = wvs[bl*77 + 76];   f1 = p.x[((size_t)b*T_ + t)*3 + 0]; }
      else               { f0 = p.x[((size_t)b*T_ + t)*3 + 1]; f1 = p.x[((size_t)b*T_ + t)*3 + 2]; }
      stc_u(p.fwv + ((size_t)t*64 + b)*40 + pr, pkf(f0, f1));
    }
    __syncthreads();
    add_cnt(p.flags, 1, t);
  }
}

// ---- L2/L3 staging: phase ph stages pairs [ph*112, ph*112+112) ----
__device__ __forceinline__ void stage_l23(u32* pan, int tid, int ph, int t,
    const u32* fwvt, const u32* hint, const u32* rect, const float* h0f) {
  u32 tmp[28];
#pragma unroll
  for (int it = 0; it < 28; ++it) {
    int idx = tid + it*256;
    int b = idx/112, pl = idx - b*112;
    int gp = ph*112 + pl;
    u32 v;
    if (gp < 40) v = fwvt[b*40 + gp];
    else if (gp < 240) v = hint[b*200 + gp - 40];
    else if (gp < 440) {
      if (t == 0) { float2 f = *(const float2*)(h0f + (size_t)b*H_ + 2*(gp-240)); v = pkf(f.x, f.y); }
      else v = rect[b*200 + gp - 240];
    } else v = 0u;
    tmp[it] = v;
  }
#pragma unroll
  for (int it = 0; it < 28; ++it) {
    int idx = tid + it*256;
    int b = idx/112, pl = idx - b*112;
    pan[b*116 + pl] = tmp[it];
  }
}

// ================= L2/L3 =================
template <int L>
__device__ void lstm_role(const P& p, int wg, char* smem) {
  const int tid = threadIdx.x;
  const int w = tid >> 6, l = tid & 63;
  const int ul = (w&1)*4 + (l>>4);
  const int u  = wg*8 + ul;
  const int bA = (w>>1)*32 + (l&15), bB = bA + 16;
  constexpr int STG = (L==2) ? 2 : 3;
  _Float16* wgW = ((L==2) ? p.w2f : p.w3f) + (size_t)wg * W2WG;
  const float* wih = (L==2) ? p.wih2 : p.wih3;
  const float* whh = (L==2) ? p.whh2 : p.whh3;
  const float* bih = (L==2) ? p.bih2 : p.bih3;
  const float* bhh = (L==2) ? p.bhh2 : p.bhh3;
  const u32* hin = (L==2) ? p.fh1 : p.fh2;
  u32* rec = (L==2) ? p.fh2 : p.fh3;
  _Float16* panA = (_Float16*)smem;
  _Float16* panB = panA + 64*SW2;

  // prepack [ks28][row32][q4][i8]; K-order [wv77 | x3 | hin400 | rec400 | pad16]
  for (int e = tid; e < 28672; e += 256) {
    int i = e & 7, q = (e>>3)&3, row = (e>>5)&31, ks = e>>10;
    int k = ks*32 + q*8 + i;
    int cu = row>>2, g = row&3;
    int r = g*400 + wg*8 + cu;
    float v;
    if (k < 77)       v = wih[(size_t)r*480 + 403 + k];
    else if (k < 80)  v = wih[(size_t)r*480 + (k-77)];
    else if (k < 480) v = wih[(size_t)r*480 + 3 + (k-80)];
    else if (k < 880) v = whh[(size_t)r*400 + (k-480)];
    else              v = 0.f;
    wgW[e] = (_Float16)v;
  }
  float bsum[4];
#pragma unroll
  for (int g = 0; g < 4; ++g) bsum[g] = bih[g*400+u] + bhh[g*400+u];
  float creg[2];
  creg[0] = p.c0[(size_t)(L-1)*B_*H_ + (size_t)bA*H_ + u];
  creg[1] = p.c0[(size_t)(L-1)*B_*H_ + (size_t)bB*H_ + u];
  __syncthreads();

  for (int t = 0; t < T_; ++t) {
    f32x4 acc0 = {0.f,0.f,0.f,0.f}, acc1 = {0.f,0.f,0.f,0.f};
    if (L == 2) wait_cnt(p.flags, 1, t, CNT1);      // implies stage0(t)
    else        wait_cnt(p.flags, 2, t, CNT2);
    const u32* fwvt = p.fwv + (size_t)t*64*40;
    const u32* hint = hin + (size_t)t*64*200;
    const u32* rect = rec + (size_t)(t-1)*64*200;   // valid t>0
    const float* h0f = p.h0 + (size_t)(L-1)*B_*H_;
    // S0 (wv+x+hin pairs 0..111) -> panA
    stage_l23((u32*)panA, tid, 0, t, fwvt, hint, rect, h0f);
    __syncthreads();
    // S1 (hin pairs 72..183 == gp 112..223) -> panB || M0(panA)
    {
      u32 tmp[28];
#pragma unroll
      for (int it = 0; it < 28; ++it) {
        int idx = tid + it*256;
        int b = idx/112, pl = idx - b*112;
        tmp[it] = hint[b*200 + 72 + pl];   // gp = 112+pl -> hin pair gp-40
      }
      mfma_chunk7(panA, SW2, wgW, w, l, acc0, acc1);
#pragma unroll
      for (int it = 0; it < 28; ++it) {
        int idx = tid + it*256;
        int b = idx/112, pl = idx - b*112;
        ((u32*)panB)[b*116 + pl] = tmp[it];
      }
    }
    // own-rec wait (usually satisfied; placed after S1 so staging/M0 overlap it)
    if (t > 0) wait_cnt(p.flags, STG, t-1, CNT2); else __syncthreads();
    // S2 (hin tail + rec head) -> panA || M1(panB)
    {
      u32 tmp[28];
#pragma unroll
      for (int it = 0; it < 28; ++it) {
        int idx = tid + it*256;
        int b = idx/112, pl = idx - b*112;
        int gp = 224 + pl;
        u32 v;
        if (gp < 240) v = hint[b*200 + gp - 40];
        else if (t == 0) { float2 f = *(const float2*)(h0f + (size_t)b*H_ + 2*(gp-240)); v = pkf(f.x, f.y); }
        else v = rect[b*200 + gp - 240];
        tmp[it] = v;
      }
      mfma_chunk7(panB, SW2, wgW + 7*1024, w, l, acc0, acc1);
#pragma unroll
      for (int it = 0; it < 28; ++it) {
        int idx = tid + it*256;
        int b = idx/112, pl = idx - b*112;
        ((u32*)panA)[b*116 + pl] = tmp[it];
      }
    }
    __syncthreads();
    // S3 (rec tail + pad) -> panB || M2(panA)
    {
      u32 tmp[28];
#pragma unroll
      for (int it = 0; it < 28; ++it) {
        int idx = tid + it*256;
        int b = idx/112, pl = idx - b*112;
        int gp = 336 + pl;
        u32 v;
        if (gp < 440) {
          if (t == 0) { float2 f = *(const float2*)(h0f + (size_t)b*H_ + 2*(gp-240)); v = pkf(f.x, f.y); }
          else v = rect[b*200 + gp - 240];
        } else v = 0u;
        tmp[it] = v;
      }
      mfma_chunk7(panA, SW2, wgW + 14*1024, w, l, acc0, acc1);
#pragma unroll
      for (int it = 0; it < 28; ++it) {
        int idx = tid + it*256;
        int b = idx/112, pl = idx - b*112;
        ((u32*)panB)[b*116 + pl] = tmp[it];
      }
    }
    __syncthreads();
    mfma_chunk7(panB, SW2, wgW + 21*1024, w, l, acc0, acc1);

    float hA, hB;
    {
      float cn = sigm(acc0[1]+bsum[1])*creg[0] + sigm(acc0[0]+bsum[0])*tanhf(acc0[2]+bsum[2]);
      creg[0] = cn; hA = sigm(acc0[3]+bsum[3])*tanhf(cn);
      float cn2 = sigm(acc1[1]+bsum[1])*creg[1] + sigm(acc1[0]+bsum[0])*tanhf(acc1[2]+bsum[2]);
      creg[1] = cn2; hB = sigm(acc1[3]+bsum[3])*tanhf(cn2);
    }
    {
      float hAp = __shfl_xor(hA, 16, 64);
      float hBp = __shfl_xor(hB, 16, 64);
      if (((l>>4) & 1) == 0) {
        const int pi = wg*4 + (ul>>1);
        stc_u(rec + ((size_t)t*64 + bA)*200 + pi, pkf(hA, hAp));
        stc_u(rec + ((size_t)t*64 + bB)*200 + pi, pkf(hB, hBp));
      }
    }
    __syncthreads();
    add_cnt(p.flags, STG, t);
  }
}

// ================= OUT =================
__device__ void out_role(const P& p, int g, char* smem) {
  const int tid = threadIdx.x;
  const int cg = tid & 31, bg = tid >> 5;
  const int c0 = cg*4;
  _Float16* pan = (_Float16*)smem;
  _Float16* wofg = p.wof + (size_t)g*WOWG;
  for (int e = tid; e < 300*32*16; e += 256) {
    int kk = e >> 9, rem = e & 511;
    int cgi = rem >> 4, j4 = rem & 15;
    int j = j4 >> 2, kc = j4 & 3;
    int c = cgi*4 + j; if (c > 120) c = 120;
    wofg[e] = (_Float16)p.wout[(size_t)c*1200 + kk*4 + kc];
  }
  float bo[4];
#pragma unroll
  for (int j = 0; j < 4; ++j) {
    int c = c0 + j; if (c > 120) c = 120;
    bo[j] = p.bout[c];
  }
  __syncthreads();

  for (int t = g; t < T_; t += GOUT) {
    wait_cnt(p.flags, 3, t, CNT3);
    float acc[8][4];
#pragma unroll
    for (int r = 0; r < 8; ++r)
#pragma unroll
      for (int j = 0; j < 4; ++j) acc[r][j] = 0.f;

    for (int ph = 0; ph < 5; ++ph) {
      for (int idx = tid; idx < 7680; idx += 256) {
        int b = idx / 120, pl = idx - b*120;
        int Pp = ph*120 + pl;
        u32 pv;
        if (Pp < 200)      pv = p.fh1[((size_t)t*64 + b)*200 + Pp];
        else if (Pp < 400) pv = p.fh2[((size_t)t*64 + b)*200 + (Pp-200)];
        else               pv = p.fh3[((size_t)t*64 + b)*200 + (Pp-400)];
        ((u32*)pan)[b*122 + pl] = pv;
      }
      __syncthreads();
      const _Float16* wp = wofg + ((size_t)(ph*60)*32 + cg)*16;
#pragma unroll 3
      for (int k = 0; k < 240; k += 4) {
        h4 wa = *(const h4*)(wp);
        h4 wb = *(const h4*)(wp+4);
        h4 wc = *(const h4*)(wp+8);
        h4 wd = *(const h4*)(wp+12);
        wp += 512;
#pragma unroll
        for (int r = 0; r < 8; ++r) {
          h4 a = *(const h4*)(pan + (bg*8+r)*SWO + k);
          h2 al = lo4(a), ah = hi4(a);
          acc[r][0] = dot2(al, lo4(wa), acc[r][0]); acc[r][0] = dot2(ah, hi4(wa), acc[r][0]);
          acc[r][1] = dot2(al, lo4(wb), acc[r][1]); acc[r][1] = dot2(ah, hi4(wb), acc[r][1]);
          acc[r][2] = dot2(al, lo4(wc), acc[r][2]); acc[r][2] = dot2(ah, hi4(wc), acc[r][2]);
          acc[r][3] = dot2(al, lo4(wd), acc[r][3]); acc[r][3] = dot2(ah, hi4(wd), acc[r][3]);
        }
      }
      __syncthreads();
    }
#pragma unroll
    for (int r = 0; r < 8; ++r)
#pragma unroll
      for (int j = 0; j < 4; ++j) {
        int c = c0 + j;
        if (c < 121)
          p.out_y[((size_t)(bg*8+r)*T_ + t)*OUT_ + c] = acc[r][j] + bo[j];
      }
    __syncthreads();
  }
}

__global__ __launch_bounds__(256) void hw_pipeline(P p) {
  __shared__ __align__(16) char smem_raw[SMEM_BYTES];
  const int bid = blockIdx.x;
  if (bid < G1) lstm1_role(p, bid, smem_raw);
  else if (bid < G1+GPA) pa_role(p, bid - G1, smem_raw);
  else if (bid < G1+GPA+G2) lstm_role<2>(p, bid - G1 - GPA, smem_raw);
  else if (bid < G1+GPA+G2+G3) lstm_role<3>(p, bid - G1 - GPA - G2, smem_raw);
  else out_role(p, bid - G1 - GPA - G2 - G3, smem_raw);
}

extern "C" void kernel_launch(void* const* d_in, const int* in_sizes, int n_in,
                              void* d_out, int out_size, void* d_ws, size_t ws_size,
                              hipStream_t stream) {
  (void)in_sizes; (void)n_in; (void)out_size; (void)ws_size;
  P p;
  p.x = (const float*)d_in[0];
  p.text = (const int*)d_in[1];
  p.tmask = (const float*)d_in[2];
  p.h0 = (const float*)d_in[3];
  p.c0 = (const float*)d_in[4];
  p.pwv = (const float*)d_in[5];
  p.pkap = (const float*)d_in[6];
  p.wih1 = (const float*)d_in[7];  p.whh1 = (const float*)d_in[8];
  p.bih1 = (const float*)d_in[9];  p.bhh1 = (const float*)d_in[10];
  p.wih2 = (const float*)d_in[11]; p.whh2 = (const float*)d_in[12];
  p.bih2 = (const float*)d_in[13]; p.bhh2 = (const float*)d_in[14];
  p.wih3 = (const float*)d_in[15]; p.whh3 = (const float*)d_in[16];
  p.bih3 = (const float*)d_in[17]; p.bhh3 = (const float*)d_in[18];
  p.wwin = (const float*)d_in[19]; p.bwin = (const float*)d_in[20];
  p.wout = (const float*)d_in[21]; p.bout = (const float*)d_in[22];
  float* out = (float*)d_out;
  p.out_y  = out;
  p.out_wv = out + (size_t)B_*T_*OUT_;
  p.out_kap = p.out_wv + (size_t)B_*T_*V_;
  char* ws = (char*)d_ws;
  p.flags = (u32*)(ws + FLAGS_B);
  p.w1f = (_Float16*)(ws + W1F_B);
  p.w2f = (_Float16*)(ws + W2F_B);
  p.w3f = (_Float16*)(ws + W3F_B);
  p.wof = (_Float16*)(ws + WOF_B);
  p.wwf = (u32*)(ws + WWF_B);
  p.fwv = (u32*)(ws + FWV_B);
  p.fh1 = (u32*)(ws + FH1_B);
  p.fh2 = (u32*)(ws + FH2_B);
  p.fh3 = (u32*)(ws + FH3_B);
  (void)hipMemsetAsync(ws + FLAGS_B, 0, FLAGS_SZ, stream);
  hipLaunchKernelGGL(hw_pipeline, dim3(NBLK), dim3(256), 0, stream, p);
}